// Round 1
// 356.483 us; speedup vs baseline: 1.1872x; 1.1872x over previous
//
#include <hip/hip_runtime.h>

#define NN 8192
#define CC 512
#define DKK 64

typedef float f32x4 __attribute__((ext_vector_type(4)));
typedef float f32x16 __attribute__((ext_vector_type(16)));
typedef _Float16 f16x8 __attribute__((ext_vector_type(8)));
typedef _Float16 f16x4 __attribute__((ext_vector_type(4)));

__device__ __forceinline__ f32x4 mfma16(f16x8 a, f16x8 b, f32x4 c) {
    return __builtin_amdgcn_mfma_f32_16x16x32_f16(a, b, c, 0, 0, 0);
}
__device__ __forceinline__ f32x16 mfma32(f16x8 a, f16x8 b, f32x16 c) {
    return __builtin_amdgcn_mfma_f32_32x32x16_f16(a, b, c, 0, 0, 0);
}
__device__ __forceinline__ f16x8 scl8(f16x8 v, float f) {
    _Float16 h = (_Float16)f;
    f16x8 r;
#pragma unroll
    for (int i = 0; i < 8; i++) r[i] = v[i] * h;
    return r;
}

// ---- all weight transposes in one launch. grid 1280 x 256.
// Wqt: 64*512 = 32768; Wkt: 32768; Wvf: 512*512 = 262144. Total 327680.
__global__ void wtrans_all_kernel(const float* __restrict__ Wq, const float* __restrict__ Wk,
                                  const float* __restrict__ Wv,
                                  _Float16* __restrict__ Wqt, _Float16* __restrict__ Wkt,
                                  _Float16* __restrict__ Wvf) {
    int idx = blockIdx.x * 256 + threadIdx.x;
    if (idx < 32768) {
        int n = idx >> 9, k = idx & 511;
        Wqt[idx] = (_Float16)Wq[k * 64 + n];
    } else if (idx < 65536) {
        int j = idx - 32768;
        int n = j >> 9, k = j & 511;
        Wkt[j] = (_Float16)Wk[k * 64 + n];
    } else {
        int j = idx - 65536;
        int k16 = j & 15, c = (j >> 4) & 511, ks = j >> 13;
        Wvf[j] = (_Float16)Wv[(size_t)(16 * ks + k16) * 512 + c];
    }
}

// ---- fused Q+K projection: Q[N][64] row-major f16; K -> frag-major
// Kf[tile=n>>6][ks=dk>>4][kv6=n&63][k16=dk&15]
__global__ __launch_bounds__(256) void proj_qk2_kernel(
    const float* __restrict__ im1, const float* __restrict__ im2,
    const _Float16* __restrict__ Wqt, const _Float16* __restrict__ Wkt,
    _Float16* __restrict__ Q1, _Float16* __restrict__ Kf1,
    _Float16* __restrict__ Q2, _Float16* __restrict__ Kf2)
{
    const float* X = blockIdx.y ? im2 : im1;
    _Float16* Q = blockIdx.y ? Q2 : Q1;
    _Float16* Kf = blockIdx.y ? Kf2 : Kf1;

    __shared__ __align__(16) _Float16 Wlds[128 * 512];  // 128 KB

    const int tid = threadIdx.x;
    const int lane = tid & 63, wave = tid >> 6;
    const int n16 = lane & 15, quad = lane >> 4;

#pragma unroll
    for (int i = 0; i < 32; i++) {
        const int idx = tid + 256 * i;
        const int row = idx >> 6, ch = idx & 63;
        const _Float16* src = (row < 64) ? (Wqt + (size_t)row * 512 + ch * 8)
                                         : (Wkt + (size_t)(row - 64) * 512 + ch * 8);
        *(f16x8*)&Wlds[row * 512 + ((ch ^ (row & 7)) * 8)] = *(const f16x8*)src;
    }
    __syncthreads();

    const int arow = blockIdx.x * 64 + wave * 16 + n16;
    f32x4 acc[8];
#pragma unroll
    for (int i = 0; i < 8; i++) acc[i] = (f32x4){0.f, 0.f, 0.f, 0.f};

    const float* xbase = X + (size_t)arow * 512 + quad * 8;
    for (int kk = 0; kk < 16; kk++) {
        f32x4 xa = *(const f32x4*)(xbase + kk * 32);
        f32x4 xb = *(const f32x4*)(xbase + kk * 32 + 4);
        f16x8 afrag;
#pragma unroll
        for (int j = 0; j < 4; j++) { afrag[j] = (_Float16)xa[j]; afrag[4 + j] = (_Float16)xb[j]; }
#pragma unroll
        for (int t = 0; t < 8; t++) {
            const int row = t * 16 + n16;
            f16x8 bfr = *(const f16x8*)&Wlds[row * 512 + (((4 * kk + quad) ^ (row & 7)) * 8)];
            acc[t] = mfma16(afrag, bfr, acc[t]);
        }
    }
    const int rbase = blockIdx.x * 64 + wave * 16 + quad * 4;
#pragma unroll
    for (int t = 0; t < 4; t++)
#pragma unroll
        for (int r = 0; r < 4; r++) {
            Q[(size_t)(rbase + r) * 64 + t * 16 + n16] = (_Float16)acc[t][r];
            Kf[((size_t)(blockIdx.x * 4 + t) * 64 + (wave * 16 + quad * 4 + r)) * 16 + n16] =
                (_Float16)acc[4 + t][r];
        }
}

// ---- V projection -> frag-major Vf[tile][ks=n6>>4][c=512][n16]
__global__ __launch_bounds__(256) void proj_vt_kernel(
    const float* __restrict__ im1, const float* __restrict__ im2,
    const _Float16* __restrict__ Wvf,
    _Float16* __restrict__ Vf1, _Float16* __restrict__ Vf2)
{
    const float* X = blockIdx.y ? im2 : im1;
    _Float16* Vf = blockIdx.y ? Vf2 : Vf1;
    const int n0 = blockIdx.x * 32;
    const int tid = threadIdx.x;
    const int lane = tid & 63, wave = tid >> 6;
    const int l31 = lane & 31, lhi = lane >> 5;

    __shared__ __align__(16) _Float16 Xlds[32 * 512];

#pragma unroll
    for (int i = 0; i < 8; i++) {
        const int n = tid >> 3;
        const int chunk = (tid & 7) + 8 * i;
        const float* xp = X + (size_t)(n0 + n) * CC + chunk * 8;
        f32x4 x0 = *(const f32x4*)xp;
        f32x4 x1 = *(const f32x4*)(xp + 4);
        f16x8 d;
#pragma unroll
        for (int j = 0; j < 4; j++) { d[j] = (_Float16)x0[j]; d[4 + j] = (_Float16)x1[j]; }
        *(f16x8*)&Xlds[n * 512 + ((chunk ^ (n & 7)) * 8)] = d;
    }
    __syncthreads();

    f32x16 acc[4];
#pragma unroll
    for (int t = 0; t < 4; t++)
#pragma unroll
        for (int r = 0; r < 16; r++) acc[t][r] = 0.f;

    for (int ks = 0; ks < 32; ks++) {
        f16x8 xb = *(const f16x8*)&Xlds[l31 * 512 + (((2 * ks + lhi) ^ (l31 & 7)) * 8)];
#pragma unroll
        for (int ct = 0; ct < 4; ct++) {
            const _Float16* wp = Wvf + ((size_t)ks * 512 + 128 * wave + 32 * ct + l31) * 16 + 8 * lhi;
            acc[ct] = mfma32(*(const f16x8*)wp, xb, acc[ct]);
        }
    }
    const int tile = n0 >> 6;
    const int ksbase = (n0 & 32) >> 4;  // 0 or 2
#pragma unroll
    for (int ct = 0; ct < 4; ct++)
#pragma unroll
        for (int r = 0; r < 16; r++) {
            const int c = 128 * wave + 32 * ct + (r & 3) + 8 * (r >> 2) + 4 * lhi;
            const int ks = ksbase + (l31 >> 4);
            Vf[((size_t)(tile * 4 + ks) * 512 + c) * 16 + (l31 & 15)] = (_Float16)acc[ct][r];
        }
}

// ---- flash6: occupancy-first restructure. 32-q blocks, grid (256,2)=512 blocks,
// 8 waves, 4 kv-tiles/slot (32 slots). Wave w: QK stream (g=w>>1, a=w&1) computes
// 32kv x 32q quarter of tile t=4s+g; PV: each wave owns cols 64w..64w+63 over ALL
// 4 tiles (full online merge of 8 (g,a) streams -> no cross-wave epilogue merge).
// acc = 2 x f32x16 = 32 AGPR; LDS 36 KB; launch_bounds(512,4) -> <=128 regs/wave
// -> 4 waves/SIMD x 2 blocks/CU = 16 waves/CU (2x flash5).
__global__ __launch_bounds__(512, 4) void flash6_kernel(
    const _Float16* __restrict__ Q1, const _Float16* __restrict__ Kf1,
    const _Float16* __restrict__ Q2, const _Float16* __restrict__ Kf2,
    const _Float16* __restrict__ Vf1, const _Float16* __restrict__ Vf2,
    const float* __restrict__ im1, const float* __restrict__ im2,
    float* __restrict__ out)
{
    const int img = blockIdx.y;
    const _Float16* Q = img ? Q1 : Q2;
    const _Float16* Kf = img ? Kf2 : Kf1;
    const _Float16* Vf = img ? Vf2 : Vf1;
    const float* res = img ? im2 : im1;
    float* o = out + (size_t)img * NN * CC;

    // P[buf][g][chunk=kv>>3][q=32][kv&7] f16, chunk-major (conflict-free) = 32 KB
    __shared__ __align__(16) _Float16 P[2][4][8][32][8];
    __shared__ float mPart[2][4][2][32];  // [buf][g][a][q]
    __shared__ float mF[4][2][32], lF[4][2][32];

    const int tid = threadIdx.x;
    const int lane = tid & 63, w = tid >> 6;
    const int l31 = lane & 31, lhi = lane >> 5;
    const int g = w >> 1, a = w & 1;
    const int qbase = blockIdx.x * 32;

    f16x8 qf[4];
    {
        const _Float16* qp = Q + (size_t)(qbase + l31) * DKK + 8 * lhi;
#pragma unroll
        for (int k = 0; k < 4; k++) qf[k] = *(const f16x8*)(qp + 16 * k);
    }

    f32x16 acc[2];  // cols 64w+32*ct, rows q (col of D = q = l31)
#pragma unroll
    for (int t = 0; t < 2; t++)
#pragma unroll
        for (int r = 0; r < 16; r++) acc[t][r] = 0.f;

    float ma_run = -3e38f, l_run = 0.f;  // own (g,a) QK stream
    float mg_run = -3e38f;               // merged acc reference max (all 8 streams)

    const _Float16* kb = Kf + ((size_t)(32 * a + l31)) * 16 + 8 * lhi;
    const _Float16* vb = Vf + ((size_t)(64 * w + l31)) * 16 + 8 * lhi;

    // QK for slot s: S^T quarter (32kv x 32q) of tile t=4s+g, kv rows 32a..,
    // softmax vs own stream, write chunk-major P + mPart.
    auto do_qk = [&](int s) {
        const int t = 4 * s + g;
        const int pbuf = s & 1;
        f32x16 sA;
#pragma unroll
        for (int r = 0; r < 16; r++) sA[r] = 0.f;
#pragma unroll
        for (int k = 0; k < 4; k++) {
            f16x8 kf = *(const f16x8*)(kb + (size_t)(t * 4 + k) * (64 * 16));
            sA = mfma32(kf, qf[k], sA);
        }
        // tree max over 16 r, then combine lhi halves
        float mr[8];
#pragma unroll
        for (int i = 0; i < 8; i++) mr[i] = fmaxf(sA[i], sA[i + 8]);
#pragma unroll
        for (int i = 0; i < 4; i++) mr[i] = fmaxf(mr[i], mr[i + 4]);
        float mx = fmaxf(fmaxf(mr[0], mr[1]), fmaxf(mr[2], mr[3]));
        mx = fmaxf(mx, __shfl_xor(mx, 32));
        const float manew = fmaxf(ma_run, mx);
        if (lane < 32) mPart[pbuf][g][a][lane] = manew;
        float ls = 0.f;
#pragma unroll
        for (int r = 0; r < 16; r++) {
            float p = __expf(sA[r] - manew);
            ls += p;
            sA[r] = p;
        }
        ls += __shfl_xor(ls, 32);
        l_run = l_run * __expf(ma_run - manew) + ls;
        ma_run = manew;
        // kv_local = (r&3) + 8*(r>>2) + 4*lhi -> chunk 4a+(r>>2), fine (r&3)+4*lhi
#pragma unroll
        for (int gg = 0; gg < 4; gg++) {
            f16x4 p4;
#pragma unroll
            for (int u = 0; u < 4; u++) p4[u] = (_Float16)sA[gg * 4 + u];
            *(f16x4*)&P[pbuf][g][4 * a + gg][l31][4 * lhi] = p4;
        }
    };

    do_qk(0);
    __syncthreads();

    for (int s = 0; s < 32; s++) {
        const int pbuf = s & 1;

        // early V-frag issue for PV(s) k=0, all 4 tiles x 2 ct (hides L2/L3 latency
        // under QK(s+1))
        f16x8 va0[8];
#pragma unroll
        for (int tt = 0; tt < 4; tt++)
#pragma unroll
            for (int ct = 0; ct < 2; ct++)
                va0[tt * 2 + ct] = *(const f16x8*)(vb +
                    ((size_t)((4 * s + tt) * 4) * 512 + 32 * ct) * 16);

        // pipelined QK for next slot (writes other P buffer)
        if (s < 31) do_qk(s + 1);

        // ---- PV(s): merge all 8 (g,a) streams online
        float f[4][2];
        float mgn = mg_run;
#pragma unroll
        for (int g2 = 0; g2 < 4; g2++)
#pragma unroll
            for (int a2 = 0; a2 < 2; a2++) {
                f[g2][a2] = mPart[pbuf][g2][a2][l31];
                mgn = fmaxf(mgn, f[g2][a2]);
            }
        const float al = __expf(mg_run - mgn);
        mg_run = mgn;
        if (!__all(al == 1.f)) {
#pragma unroll
            for (int t = 0; t < 2; t++)
#pragma unroll
                for (int r = 0; r < 16; r++) acc[t][r] *= al;
        }
        bool nos1 = true;
#pragma unroll
        for (int g2 = 0; g2 < 4; g2++)
#pragma unroll
            for (int a2 = 0; a2 < 2; a2++) {
                f[g2][a2] = __expf(f[g2][a2] - mgn);
                nos1 &= (f[g2][a2] == 1.f);
            }
        const bool nos = __all(nos1);

#pragma unroll
        for (int tt = 0; tt < 4; tt++)
#pragma unroll
            for (int k = 0; k < 4; k++) {
                // chunk-major P read: lanes contiguous, 0-conflict
                f16x8 pb = *(const f16x8*)&P[pbuf][tt][2 * k + lhi][l31][0];
                if (!nos) pb = scl8(pb, f[tt][k >> 1]);
#pragma unroll
                for (int ct = 0; ct < 2; ct++) {
                    f16x8 va = (k == 0) ? va0[tt * 2 + ct]
                        : *(const f16x8*)(vb +
                            ((size_t)((4 * s + tt) * 4 + k) * 512 + 32 * ct) * 16);
                    acc[ct] = mfma32(va, pb, acc[ct]);
                }
            }
        __syncthreads();  // P(s+1)/mPart written by all; P(s) reads done
    }

    // ---- epilogue: per-lane denominator from 8 streams; direct store (each wave
    // owns its 64-col slice; D row = c_local, col = q = l31)
    if (lane < 32) {
        mF[g][a][lane] = ma_run;
        lF[g][a][lane] = l_run;
    }
    __syncthreads();

    const float M = mg_run;  // == max over all 8 stream maxima (exact)
    float den = 0.f;
#pragma unroll
    for (int g2 = 0; g2 < 4; g2++)
#pragma unroll
        for (int a2 = 0; a2 < 2; a2++)
            den += lF[g2][a2][l31] * __expf(mF[g2][a2][l31] - M);
    const float fac = 1.f / den;

#pragma unroll
    for (int ct = 0; ct < 2; ct++)
#pragma unroll
        for (int rg = 0; rg < 4; rg++) {
            const int c = 64 * w + 32 * ct + 8 * rg + 4 * lhi;
            const size_t off = (size_t)(qbase + l31) * CC + c;
            f32x4 v;
#pragma unroll
            for (int u = 0; u < 4; u++) v[u] = acc[ct][4 * rg + u] * fac;
            f32x4 r4 = *(const f32x4*)(res + off);
            *(f32x4*)(o + off) = v + r4;
        }
}

extern "C" void kernel_launch(void* const* d_in, const int* in_sizes, int n_in,
                              void* d_out, int out_size, void* d_ws, size_t ws_size,
                              hipStream_t stream) {
    const float* im1 = (const float*)d_in[0];
    const float* im2 = (const float*)d_in[1];
    const float* Wq  = (const float*)d_in[2];
    const float* Wk  = (const float*)d_in[3];
    const float* Wv  = (const float*)d_in[4];
    float* out = (float*)d_out;

    _Float16* w = (_Float16*)d_ws;
    _Float16* Wqt = w;                      // 64*512
    _Float16* Wkt = Wqt + 64 * 512;
    _Float16* Wvf = Wkt + 64 * 512;         // 512*512 frag-major
    _Float16* Q1  = Wvf + 512 * 512;        // 8192*64 each
    _Float16* Kf1 = Q1 + NN * DKK;
    _Float16* Q2  = Kf1 + NN * DKK;
    _Float16* Kf2 = Q2 + NN * DKK;
    _Float16* Vf1 = Kf2 + NN * DKK;         // frag-major [128][4][512][16] each
    _Float16* Vf2 = Vf1 + (size_t)CC * NN;

    wtrans_all_kernel<<<1280, 256, 0, stream>>>(Wq, Wk, Wv, Wqt, Wkt, Wvf);
    proj_qk2_kernel<<<dim3(128, 2), 256, 0, stream>>>(im1, im2, Wqt, Wkt, Q1, Kf1, Q2, Kf2);
    proj_vt_kernel<<<dim3(256, 2), 256, 0, stream>>>(im1, im2, Wvf, Vf1, Vf2);
    flash6_kernel<<<dim3(256, 2), 512, 0, stream>>>(Q1, Kf1, Q2, Kf2, Vf1, Vf2, im1, im2, out);
}